// Round 6
// baseline (74.662 us; speedup 1.0000x reference)
//
#include <hip/hip_runtime.h>
#include <math.h>

// Chamfer loss: B=4, N=M=8192, D=3, fp32.
// Columns pre-packed as (x, y, z, ||g||^2) float4 in global memory; the inner
// loop reads them at wave-UNIFORM indices -> compiler emits s_load_dwordx4/x8
// (scalar path). No LDS, no VMEM in the hot loop. Per column-pair per row:
// 6 v_fma + 1 v_min3 (+ v_mov for gn, amortized over IT rows) = 3.75 ops/pair.
// ws: [B*(N+M)] u32 min-bits | [RB1] f32 partials | pad | [B*N + B*M] float4 packed.

#define THREADS 256
#define IT 4                  // rows per thread (register blocked)
#define PB (THREADS * IT)     // 1024 rows per block
#define MC 512                // columns per block (16 atomic writers / row)
#define RB1 64                // stage-1 reduce blocks

// Fused: init mins to +inf AND build packed arrays for P and G.
__global__ __launch_bounds__(256) void pack_init_kernel(
    const float* __restrict__ P, const float* __restrict__ G,
    float4* __restrict__ packP, float4* __restrict__ packG,
    unsigned* __restrict__ mins, int nP, int nG) {
    int i = blockIdx.x * blockDim.x + threadIdx.x;
    int tot = nP + nG;
    if (i >= tot) return;
    mins[i] = 0x7F800000u;  // +inf bits
    const float* s;
    float4* d;
    int k;
    if (i < nP) { s = P; d = packP; k = i; }
    else        { s = G; d = packG; k = i - nP; }
    float x = s[3 * (size_t)k], y = s[3 * (size_t)k + 1], z = s[3 * (size_t)k + 2];
    d[k] = make_float4(x, y, z, fmaf(x, x, fmaf(y, y, z * z)));
}

// grid: (N/PB, M/MC, 2*B).  z < B: pred->gt; z >= B: gt->pred.
__global__ __launch_bounds__(THREADS) void chamfer_min_kernel(
    const float4* __restrict__ packP, const float4* __restrict__ packG,
    unsigned* __restrict__ mins1, unsigned* __restrict__ mins2,
    int N, int M) {
    int z = blockIdx.z;
    int B = gridDim.z >> 1;
    const float4* rowp; const float4* colp; unsigned* out;
    if (z < B) {
        rowp = packP + (size_t)z * N;
        colp = packG + (size_t)z * M;
        out  = mins1 + (size_t)z * N;
    } else {
        int b = z - B;
        rowp = packG + (size_t)b * M;
        colp = packP + (size_t)b * N;
        out  = mins2 + (size_t)b * M;
    }
    int row0 = blockIdx.x * PB;
    const float4* __restrict__ col = colp + (size_t)blockIdx.y * MC;  // uniform

    float a1[IT], a2[IT], a3[IT], pn[IT], mn[IT];
#pragma unroll
    for (int i = 0; i < IT; ++i) {
        int r = row0 + threadIdx.x + i * THREADS;
        float4 p = rowp[r];                    // per-lane vector load (once)
        a1[i] = -2.0f * p.x;
        a2[i] = -2.0f * p.y;
        a3[i] = -2.0f * p.z;
        pn[i] = p.w;
        mn[i] = INFINITY;
    }

#pragma unroll 4
    for (int j = 0; j < MC; j += 2) {
        float4 g0 = col[j];        // uniform index -> s_load_dwordx4 (SMEM)
        float4 g1 = col[j + 1];
#pragma unroll
        for (int i = 0; i < IT; ++i) {
            // gn - 2 p.g  (pn added after the min; min is shift-invariant)
            float t0 = fmaf(g0.x, a1[i], fmaf(g0.y, a2[i], fmaf(g0.z, a3[i], g0.w)));
            float t1 = fmaf(g1.x, a1[i], fmaf(g1.y, a2[i], fmaf(g1.z, a3[i], g1.w)));
            mn[i] = fminf(fminf(t0, t1), mn[i]);   // -> v_min3_f32
        }
    }

#pragma unroll
    for (int i = 0; i < IT; ++i) {
        int r = row0 + threadIdx.x + i * THREADS;
        float d = fmaxf(pn[i] + mn[i], 0.0f);   // >= 0 so uint order == float order
        atomicMin(&out[r], __float_as_uint(d));
    }
}

// Stage 1: RB1 blocks, each sums a contiguous slice of the mins.
__global__ __launch_bounds__(256) void reduce1_kernel(
    const unsigned* __restrict__ mins, int n1, int n2,
    float* __restrict__ partials) {
    int total = n1 + n2;
    int per_block = total / RB1;               // 1024
    int base = blockIdx.x * per_block;
    float w1 = 0.5f / (float)n1;
    float w2 = 0.5f / (float)n2;

    float acc = 0.0f;
    for (int i = threadIdx.x; i < per_block; i += blockDim.x) {
        int idx = base + i;
        float v = __uint_as_float(mins[idx]);
        float w = (idx < n1) ? w1 : w2;
        acc += w * sqrtf(v);
    }
#pragma unroll
    for (int off = 32; off > 0; off >>= 1)
        acc += __shfl_down(acc, off, 64);

    __shared__ float sdata[4];
    int lane = threadIdx.x & 63;
    int wave = threadIdx.x >> 6;
    if (lane == 0) sdata[wave] = acc;
    __syncthreads();
    if (threadIdx.x == 0)
        partials[blockIdx.x] = sdata[0] + sdata[1] + sdata[2] + sdata[3];
}

// Stage 2: one wave sums the RB1 partials (fixed order -> deterministic).
__global__ __launch_bounds__(64) void reduce2_kernel(
    const float* __restrict__ partials, float* __restrict__ out) {
    float acc = (threadIdx.x < RB1) ? partials[threadIdx.x] : 0.0f;
#pragma unroll
    for (int off = 32; off > 0; off >>= 1)
        acc += __shfl_down(acc, off, 64);
    if (threadIdx.x == 0) out[0] = acc;
}

extern "C" void kernel_launch(void* const* d_in, const int* in_sizes, int n_in,
                              void* d_out, int out_size, void* d_ws, size_t ws_size,
                              hipStream_t stream) {
    const float* P = (const float*)d_in[0];
    const float* G = (const float*)d_in[1];
    const int B = 4;
    const int N = in_sizes[0] / (B * 3);   // 8192
    const int M = in_sizes[1] / (B * 3);   // 8192

    // ws layout
    unsigned* mins = (unsigned*)d_ws;                           // B*(N+M) u32
    float* partials = (float*)(mins + (size_t)B * (N + M));     // RB1 f32
    size_t off = (size_t)B * (N + M) * 4 + RB1 * 4;
    off = (off + 15) & ~(size_t)15;                             // 16B align
    float4* packP = (float4*)((char*)d_ws + off);               // B*N float4
    float4* packG = packP + (size_t)B * N;                      // B*M float4

    int tot = B * (N + M);
    pack_init_kernel<<<(tot + 255) / 256, 256, 0, stream>>>(
        P, G, packP, packG, mins, B * N, B * M);

    dim3 grid(N / PB, M / MC, 2 * B);      // (8, 16, 8) = 1024 blocks
    chamfer_min_kernel<<<grid, THREADS, 0, stream>>>(
        packP, packG, mins, mins + (size_t)B * N, N, M);

    reduce1_kernel<<<RB1, 256, 0, stream>>>(mins, B * N, B * M, partials);
    reduce2_kernel<<<1, 64, 0, stream>>>(partials, (float*)d_out);
}